// Round 6
// baseline (345.275 us; speedup 1.0000x reference)
//
#include <hip/hip_runtime.h>
#include <hip/hip_bf16.h>
#include <math.h>

#define Bsz 2
#define Sq  2048
#define Dm  2048
#define Hn  16
#define KVn 4
#define HDn 128

typedef __attribute__((ext_vector_type(8))) short bf16x8;
typedef __attribute__((ext_vector_type(4))) float f32x4;
typedef __attribute__((ext_vector_type(16))) float f32x16;
typedef __attribute__((ext_vector_type(4))) unsigned int u32x4;

__device__ __forceinline__ short f2b(float f) {
    __hip_bfloat16 h = __float2bfloat16(f);
    return *reinterpret_cast<short*>(&h);
}
__device__ __forceinline__ float b2f(short s) {
    __hip_bfloat16 h = *reinterpret_cast<__hip_bfloat16*>(&s);
    return __bfloat162float(h);
}
// pack two f32 -> one u32 of 2 bf16 (lo, hi) in one instruction
__device__ __forceinline__ unsigned pk2(float lo, float hh) {
    unsigned r;
    asm("v_cvt_pk_bf16_f32 %0, %1, %2" : "=v"(r) : "v"(lo), "v"(hh));
    return r;
}

// ---------------- fp32 -> bf16 elementwise (x) ----------------
__global__ __launch_bounds__(256) void f2b_kernel(
    const float* __restrict__ X, short* __restrict__ Y, int n4)
{
    int i = blockIdx.x * 256 + threadIdx.x;
    if (i >= n4) return;
    float4 v = ((const float4*)X)[i];
    short4 o;
    o.x = f2b(v.x); o.y = f2b(v.y); o.z = f2b(v.z); o.w = f2b(v.w);
    ((short4*)Y)[i] = o;
}

// ------------- ALL weights -> transposed bf16 in one launch -------------
__global__ __launch_bounds__(256) void wconv_all_kernel(
    const float* __restrict__ wq, const float* __restrict__ wk,
    const float* __restrict__ wv, const float* __restrict__ wo,
    short* __restrict__ wqkvT, short* __restrict__ woT)
{
    __shared__ float t[32][33];
    const int n0 = blockIdx.x * 32;   // global output row
    const int k0 = blockIdx.y * 32;
    const int tx = threadIdx.x, ty = threadIdx.y;

    const float* W; int Nsec, nloc; short* dst;
    if (n0 < 2048)      { W = wq; Nsec = 2048; nloc = n0;        dst = wqkvT + (size_t)n0 * Dm; }
    else if (n0 < 2560) { W = wk; Nsec = 512;  nloc = n0 - 2048; dst = wqkvT + (size_t)n0 * Dm; }
    else if (n0 < 3072) { W = wv; Nsec = 512;  nloc = n0 - 2560; dst = wqkvT + (size_t)n0 * Dm; }
    else                { W = wo; Nsec = 2048; nloc = n0 - 3072; dst = woT + (size_t)(n0 - 3072) * Dm; }

#pragma unroll
    for (int r = 0; r < 4; ++r) {
        const int row = ty + 8 * r;
        t[row][tx] = W[(size_t)(k0 + row) * Nsec + nloc + tx];
    }
    __syncthreads();
#pragma unroll
    for (int r = 0; r < 4; ++r) {
        const int row = ty + 8 * r;
        dst[(size_t)row * Dm + k0 + tx] = f2b(t[tx][row]);
    }
}

// ---------------- bf16 MFMA GEMM: C(MxN) = A(MxK) * Bt(NxK)^T ----------------
template <typename OT>
__global__ __launch_bounds__(256) void gemm_bt_kernel(
    const short* __restrict__ A, const short* __restrict__ Bt,
    OT* __restrict__ C, int M, int N, int K)
{
    __shared__ __align__(16) short As[128 * 64];
    __shared__ __align__(16) short Bs[128 * 64];

    const int tid  = threadIdx.x;
    const int w    = tid >> 6;
    const int lane = tid & 63;
    const int m16  = lane & 15;
    const int g4   = lane >> 4;
    const int wm   = w >> 1, wn = w & 1;

    const int row0 = blockIdx.y * 128;
    const int col0 = blockIdx.x * 128;

    const short* Ab = A  + (size_t)row0 * K;
    const short* Bb = Bt + (size_t)col0 * K;

    const int trow = tid >> 3;
    const int soct = (tid & 7) ^ (trow & 7);

    f32x4 acc[4][4];
#pragma unroll
    for (int i = 0; i < 4; ++i)
#pragma unroll
        for (int j = 0; j < 4; ++j) acc[i][j] = (f32x4){0.f, 0.f, 0.f, 0.f};

    for (int k0 = 0; k0 < K; k0 += 64) {
#pragma unroll
        for (int r = 0; r < 4; ++r) {
            const short* gp = Ab + (size_t)(r * 32 + trow) * K + k0 + soct * 8;
            short* lp = &As[(size_t)(r * 256 + w * 64) * 8];
            __builtin_amdgcn_global_load_lds(
                (const __attribute__((address_space(1))) void*)gp,
                (__attribute__((address_space(3))) void*)lp, 16, 0, 0);
        }
#pragma unroll
        for (int r = 0; r < 4; ++r) {
            const short* gp = Bb + (size_t)(r * 32 + trow) * K + k0 + soct * 8;
            short* lp = &Bs[(size_t)(r * 256 + w * 64) * 8];
            __builtin_amdgcn_global_load_lds(
                (const __attribute__((address_space(1))) void*)gp,
                (__attribute__((address_space(3))) void*)lp, 16, 0, 0);
        }
        __syncthreads();

#pragma unroll
        for (int kc = 0; kc < 2; ++kc) {
            bf16x8 a[4], b[4];
            const int swz = (kc * 4 + g4) ^ (m16 & 7);
#pragma unroll
            for (int s = 0; s < 4; ++s) {
                const int rowA = wm * 64 + s * 16 + m16;
                a[s] = *(const bf16x8*)&As[rowA * 64 + swz * 8];
                const int rowB = wn * 64 + s * 16 + m16;
                b[s] = *(const bf16x8*)&Bs[rowB * 64 + swz * 8];
            }
#pragma unroll
            for (int i = 0; i < 4; ++i)
#pragma unroll
                for (int j = 0; j < 4; ++j)
                    acc[i][j] = __builtin_amdgcn_mfma_f32_16x16x32_bf16(
                        a[i], b[j], acc[i][j], 0, 0, 0);
        }
        __syncthreads();
    }

#pragma unroll
    for (int i = 0; i < 4; ++i) {
        const int mbase = row0 + wm * 64 + i * 16 + g4 * 4;
#pragma unroll
        for (int j = 0; j < 4; ++j) {
            const int n = col0 + wn * 64 + j * 16 + m16;
#pragma unroll
            for (int r = 0; r < 4; ++r) {
                if constexpr (sizeof(OT) == 2)
                    C[(size_t)(mbase + r) * N + n] = f2b(acc[i][j][r]);
                else
                    C[(size_t)(mbase + r) * N + n] = acc[i][j][r];
            }
        }
    }
}

// ------------- RoPE (Q and K in one launch): one thread per (b,s,i) -------------
__global__ __launch_bounds__(256) void rope_all_kernel(
    const short* __restrict__ C3b, short* __restrict__ Qb, short* __restrict__ Kb,
    const int* __restrict__ pos_ids, float qscale, int total)
{
    int idx = blockIdx.x * blockDim.x + threadIdx.x;
    if (idx >= total) return;
    const int i = idx & 63;
    int rest = idx >> 6;
    const int s = rest % Sq;
    const int b = rest / Sq;

    const int pos = pos_ids[b * Sq + s];
    const float e   = -(float)(2 * i) * (1.0f / (float)HDn);
    const float inv = exp2f(e * 18.931568569324174f);   // log2(500000)
    const float f   = (float)pos * inv;
    float sn, c;
    sincosf(f, &sn, &c);

    const short* src = C3b + ((size_t)(b * Sq + s)) * 3072;

#pragma unroll
    for (int h = 0; h < Hn; ++h) {
        const float x1 = b2f(src[h * HDn + i]);
        const float x2 = b2f(src[h * HDn + i + 64]);
        const size_t dst = (((size_t)b * Hn + h) * Sq + s) * HDn;
        Qb[dst + i]      = f2b((x1 * c - x2 * sn) * qscale);
        Qb[dst + i + 64] = f2b((x2 * c + x1 * sn) * qscale);
    }
#pragma unroll
    for (int h = 0; h < KVn; ++h) {
        const float x1 = b2f(src[2048 + h * HDn + i]);
        const float x2 = b2f(src[2048 + h * HDn + i + 64]);
        const size_t dst = (((size_t)b * KVn + h) * Sq + s) * HDn;
        Kb[dst + i]      = f2b(x1 * c - x2 * sn);
        Kb[dst + i + 64] = f2b(x2 * c + x1 * sn);
    }
}

// ------------- V region of bf16 C3 -> transposed (B,KV,HD,S) bf16 -------------
__global__ __launch_bounds__(256) void vconv_kernel(
    const short* __restrict__ C3b, short* __restrict__ Vt)
{
    __shared__ short t[32][34];
    const int bk = blockIdx.z;
    const int b  = bk >> 2, kv = bk & 3;
    const int s0 = blockIdx.x * 32;
    const int d0 = blockIdx.y * 32;
    const int tx = threadIdx.x, ty = threadIdx.y;

#pragma unroll
    for (int r = 0; r < 4; ++r) {
        const int row = ty + 8 * r;
        t[row][tx] = C3b[((size_t)(b * Sq + s0 + row)) * 3072 + 2560 + kv * HDn + d0 + tx];
    }
    __syncthreads();
#pragma unroll
    for (int r = 0; r < 4; ++r) {
        const int row = ty + 8 * r;
        Vt[((size_t)bk * HDn + d0 + row) * Sq + s0 + tx] = t[tx][row];
    }
}

// ------------- Block-cooperative MFMA flash attention, 32x32 swapped-operand ----
// Macro-structure identical to R5 (512 blocks x 4 waves, 2/CU, nested 64-row
// tile pair htA=31-p / htB=p, one staging stream of 32-p chunks). Per-chunk
// body rewritten around mfma_f32_32x32x16_bf16 computing S[key][q]:
//  - each wave covers 32 q = 16 A-rows (lanes 0-15 of each half) + 16 B-rows
//    (lanes 16-31); q = col = lane&31 is LANE-LOCAL for softmax (no 16-group
//    shuffles; one shfl_xor(·,32) joins the two key-halves).
//  - MFMA count and LDS operand reads HALVE per unit of work vs 16x16.
//  - K staging permutation makes each lane's S-regs cover 8 consecutive
//    physical keys per frag -> P->PV repack is lane-local: 16 v_cvt_pk_bf16_f32,
//    zero cross-lane ops.
//  - After tile B's diagonal chunk (ch==p) B-lanes write out; they compute
//    dead columns afterwards (MFMA columns are independent -> no contamination).
__global__ __launch_bounds__(256, 2) void fattn_kernel(
    const short* __restrict__ Qb, const short* __restrict__ Kb,
    const short* __restrict__ Vtb, short* __restrict__ AOb)
{
    __shared__ __align__(16) short Ks[2][64 * 128];   // [buf][perm key][dim], oct-swizzled
    __shared__ __align__(16) short Vs[2][128 * 64];   // [buf][dim][key], oct-swizzled

    const int tid  = threadIdx.x;
    const int w    = tid >> 6;
    const int lane = tid & 63;
    const int l31  = lane & 31;
    const int hi   = lane >> 5;

    // balanced mapping: blocks i and i+256 get complementary p
    const int i    = blockIdx.x;
    const int half = i >> 8;
    const int k4   = i & 15;
    const int p    = half ? k4 : 15 - k4;
    const int h    = (i >> 4) & 15;
    const int b    = i >> 8;
    const int kv   = h >> 2;

    const int nch = 32 - p;              // staged/computed chunks
    const int qAb = (31 - p) * 64;       // tile A base row
    const int qBb = p * 64;              // tile B base row
    const int isB = l31 >> 4;
    const int qg  = (isB ? qBb : qAb) + w * 16 + (l31 & 15);   // this lane's q-row

    // Q fragments (B-operand): col j = l31 = q, k = hi*8+e, d = c*16 + hi*8 + e
    bf16x8 qf[8];
    {
        const short* qp = Qb + (((size_t)b * Hn + h) * Sq + qg) * HDn + hi * 8;
#pragma unroll
        for (int c = 0; c < 8; ++c) qf[c] = *(const bf16x8*)(qp + c * 16);
    }

    const short* kbase = Kb  + ((size_t)b * KVn + kv) * Sq * HDn;
    const short* vbase = Vtb + ((size_t)b * KVn + kv) * (size_t)HDn * Sq;

    // staging source pointers (identical to verified R5 staging)
    const short* gpK[4];
    const short* gpV[4];
#pragma unroll
    for (int r = 0; r < 4; ++r) {
        const int ci = r * 256 + tid;
        const int R  = ci >> 4, o = ci & 15;          // LDS K row, oct
        const int hf = (R >> 5) & 1, Rl = R & 31;
        const int phys = hf * 32 + ((Rl >> 2) & 3) * 8 + ((Rl >> 4) & 1) * 4 + (Rl & 3);
        gpK[r] = kbase + (size_t)phys * HDn + (o ^ (R & 7)) * 8;
        const int d = ci >> 3, ov = ci & 7;           // V dim row, oct
        gpV[r] = vbase + (size_t)d * Sq + (ov ^ (d & 7)) * 8;
    }

    auto stage = [&](int ktE, int buf) {
#pragma unroll
        for (int r = 0; r < 4; ++r) {
            const short* gp = gpK[r] + (size_t)ktE * HDn;
            short* lp = &Ks[buf][(size_t)(r * 256 + w * 64) * 8];
            __builtin_amdgcn_global_load_lds(
                (const __attribute__((address_space(1))) void*)gp,
                (__attribute__((address_space(3))) void*)lp, 16, 0, 0);
        }
#pragma unroll
        for (int r = 0; r < 4; ++r) {
            const short* gp = gpV[r] + ktE;
            short* lp = &Vs[buf][(size_t)(r * 256 + w * 64) * 8];
            __builtin_amdgcn_global_load_lds(
                (const __attribute__((address_space(1))) void*)gp,
                (__attribute__((address_space(3))) void*)lp, 16, 0, 0);
        }
    };

    f32x16 Ot[4];
#pragma unroll
    for (int dc = 0; dc < 4; ++dc)
#pragma unroll
        for (int e = 0; e < 16; ++e) Ot[dc][e] = 0.f;
    float mcur = -1e30f, lcur = 0.f;

    stage(0, 0);

    for (int ch = 0; ch < nch; ++ch) {
        const int cur = ch & 1;
        const int ktb = ch << 6;

        __syncthreads();                  // buf[cur] staged; prior readers of buf[cur^1] done
        if (ch + 1 < nch) stage((ch + 1) << 6, cur ^ 1);

        const short* KsC = Ks[cur];
        const short* VsC = Vs[cur];

        // ---- QK^T: S[key][q], two 32-key halves ----
        f32x16 s0, s1;
#pragma unroll
        for (int e = 0; e < 16; ++e) { s0[e] = 0.f; s1[e] = 0.f; }
        __builtin_amdgcn_s_setprio(1);
        {
            const int swz = l31 & 7;
#pragma unroll
            for (int c = 0; c < 8; ++c) {
                const int oc = ((2 * c + hi) ^ swz) * 8;
                bf16x8 k0 = *(const bf16x8*)&KsC[l31 * 128 + oc];
                bf16x8 k1 = *(const bf16x8*)&KsC[(32 + l31) * 128 + oc];
                s0 = __builtin_amdgcn_mfma_f32_32x32x16_bf16(k0, qf[c], s0, 0, 0, 0);
                s1 = __builtin_amdgcn_mfma_f32_32x32x16_bf16(k1, qf[c], s1, 0, 0, 0);
            }
        }
        __builtin_amdgcn_s_setprio(0);

        // ---- causal mask (tile B diag at ch==p; tile A diag at ch==nch-1;
        //      key>qg is automatically false for non-diagonal lanes) ----
        if (ch == p || ch == nch - 1) {
#pragma unroll
            for (int r = 0; r < 16; ++r) {
                const int koff = ktb + 8 * hi + 16 * ((r >> 2) & 1) + 4 * (r >> 3) + (r & 3);
                if (koff > qg)      s0[r] = -1e30f;
                if (koff + 32 > qg) s1[r] = -1e30f;
            }
        }

        // ---- online softmax: q is lane-local (col = l31) ----
        float mx = -1e30f;
#pragma unroll
        for (int r = 0; r < 16; ++r) mx = fmaxf(mx, fmaxf(s0[r], s1[r]));
        mx = fmaxf(mx, __shfl_xor(mx, 32));   // join the two key-halves (same q)
        if (!__all(mx <= mcur + 8.0f)) {      // T13 defer-max
            const float nm = fmaxf(mcur, mx);
            const float al = exp2f(mcur - nm);
            mcur = nm; lcur *= al;
#pragma unroll
            for (int dc = 0; dc < 4; ++dc)
#pragma unroll
                for (int e = 0; e < 16; ++e) Ot[dc][e] *= al;
        }
        float psa = 0.f, psb = 0.f;
#pragma unroll
        for (int r = 0; r < 16; ++r) {
            s0[r] = exp2f(s0[r] - mcur); psa += s0[r];
            s1[r] = exp2f(s1[r] - mcur); psb += s1[r];
        }
        float ps = psa + psb;
        ps += __shfl_xor(ps, 32);
        lcur += ps;

        // ---- pack P -> bf16 B-operand frags (lane-local; perm makes each
        //      frag cover physical keys 16*ks + 8*hi + 0..7) ----
        bf16x8 pb0, pb1, pb2, pb3;
        {
            u32x4 u;
            u[0] = pk2(s0[0],  s0[1]);  u[1] = pk2(s0[2],  s0[3]);
            u[2] = pk2(s0[8],  s0[9]);  u[3] = pk2(s0[10], s0[11]);
            pb0 = *(bf16x8*)&u;
            u[0] = pk2(s0[4],  s0[5]);  u[1] = pk2(s0[6],  s0[7]);
            u[2] = pk2(s0[12], s0[13]); u[3] = pk2(s0[14], s0[15]);
            pb1 = *(bf16x8*)&u;
            u[0] = pk2(s1[0],  s1[1]);  u[1] = pk2(s1[2],  s1[3]);
            u[2] = pk2(s1[8],  s1[9]);  u[3] = pk2(s1[10], s1[11]);
            pb2 = *(bf16x8*)&u;
            u[0] = pk2(s1[4],  s1[5]);  u[1] = pk2(s1[6],  s1[7]);
            u[2] = pk2(s1[12], s1[13]); u[3] = pk2(s1[14], s1[15]);
            pb3 = *(bf16x8*)&u;
        }

        // ---- PV: O[d][q] += V^T[d][k] * P^T[k][q] ----
        __builtin_amdgcn_s_setprio(1);
#pragma unroll
        for (int dc = 0; dc < 4; ++dc) {
            const int dR  = dc * 32 + l31;
            const int swz = l31 & 7;
            bf16x8 v0 = *(const bf16x8*)&VsC[dR * 64 + (((0 + hi) ^ swz) * 8)];
            bf16x8 v1 = *(const bf16x8*)&VsC[dR * 64 + (((2 + hi) ^ swz) * 8)];
            bf16x8 v2 = *(const bf16x8*)&VsC[dR * 64 + (((4 + hi) ^ swz) * 8)];
            bf16x8 v3 = *(const bf16x8*)&VsC[dR * 64 + (((6 + hi) ^ swz) * 8)];
            Ot[dc] = __builtin_amdgcn_mfma_f32_32x32x16_bf16(v0, pb0, Ot[dc], 0, 0, 0);
            Ot[dc] = __builtin_amdgcn_mfma_f32_32x32x16_bf16(v1, pb1, Ot[dc], 0, 0, 0);
            Ot[dc] = __builtin_amdgcn_mfma_f32_32x32x16_bf16(v2, pb2, Ot[dc], 0, 0, 0);
            Ot[dc] = __builtin_amdgcn_mfma_f32_32x32x16_bf16(v3, pb3, Ot[dc], 0, 0, 0);
        }
        __builtin_amdgcn_s_setprio(0);

        // ---- tile B complete after its diagonal chunk: write B lanes ----
        if (ch == p && isB) {
            const float inv = 1.0f / lcur;
            short* op = AOb + ((size_t)(b * Sq + qg)) * (Hn * HDn) + h * HDn + 4 * hi;
#pragma unroll
            for (int dc = 0; dc < 4; ++dc)
#pragma unroll
                for (int j = 0; j < 4; ++j) {
                    short4 o;
                    o.x = f2b(Ot[dc][4 * j + 0] * inv);
                    o.y = f2b(Ot[dc][4 * j + 1] * inv);
                    o.z = f2b(Ot[dc][4 * j + 2] * inv);
                    o.w = f2b(Ot[dc][4 * j + 3] * inv);
                    *(short4*)(op + dc * 32 + 8 * j) = o;
                }
        }
    }

    // ---- tile A epilogue (lanes 0..15 of each half) ----
    if (!isB) {
        const float inv = 1.0f / lcur;
        short* op = AOb + ((size_t)(b * Sq + qg)) * (Hn * HDn) + h * HDn + 4 * hi;
#pragma unroll
        for (int dc = 0; dc < 4; ++dc)
#pragma unroll
            for (int j = 0; j < 4; ++j) {
                short4 o;
                o.x = f2b(Ot[dc][4 * j + 0] * inv);
                o.y = f2b(Ot[dc][4 * j + 1] * inv);
                o.z = f2b(Ot[dc][4 * j + 2] * inv);
                o.w = f2b(Ot[dc][4 * j + 3] * inv);
                *(short4*)(op + dc * 32 + 8 * j) = o;
            }
    }
}

extern "C" void kernel_launch(void* const* d_in, const int* in_sizes, int n_in,
                              void* d_out, int out_size, void* d_ws, size_t ws_size,
                              hipStream_t stream)
{
    const float* x   = (const float*)d_in[0];
    const float* wq  = (const float*)d_in[1];
    const float* wk  = (const float*)d_in[2];
    const float* wv  = (const float*)d_in[3];
    const float* wo  = (const float*)d_in[4];
    const int* pos   = (const int*)d_in[6];
    float* out = (float*)d_out;

    const int M = Bsz * Sq;            // 4096
    const size_t nX  = (size_t)M * Dm; // 8388608

    short* xb    = (short*)d_ws;
    short* wqkvT = xb + nX;                       // 3072 x 2048
    short* woT   = wqkvT + (size_t)3072 * Dm;     // 2048 x 2048
    short* C3b   = woT + (size_t)Dm * Dm;         // 4096 x 3072 bf16
    short* Qb    = C3b + (size_t)M * 3072;
    short* Kb    = Qb + nX;
    short* Vtb   = Kb + (size_t)Bsz * KVn * Sq * HDn;
    short* AOb   = Vtb + (size_t)Bsz * KVn * Sq * HDn;

    // --- conversions (2 launches) ---
    f2b_kernel<<<(nX / 4 + 255) / 256, 256, 0, stream>>>(x, xb, nX / 4);
    wconv_all_kernel<<<dim3(5120 / 32, Dm / 32), dim3(32, 8), 0, stream>>>(
        wq, wk, wv, wo, wqkvT, woT);

    // --- fused QKV projection -> bf16 C3 ---
    gemm_bt_kernel<short><<<dim3(3072 / 128, M / 128), 256, 0, stream>>>(
        xb, wqkvT, C3b, M, 3072, Dm);

    // --- RoPE (Q+K) in one launch ---
    {
        const float qscale = 0.08838834764831845f * 1.4426950408889634f;
        int tot = Bsz * Sq * 64;
        rope_all_kernel<<<(tot + 255) / 256, 256, 0, stream>>>(
            C3b, Qb, Kb, pos, qscale, tot);
    }
    vconv_kernel<<<dim3(Sq / 32, HDn / 32, Bsz * KVn), dim3(32, 8), 0, stream>>>(
        C3b, Vtb);

    // --- attention: 512 blocks, nested dual-tile, 32x32 swapped-operand body ---
    fattn_kernel<<<Bsz * Hn * 16, 256, 0, stream>>>(Qb, Kb, Vtb, AOb);

    // --- output projection (fp32 out) ---
    gemm_bt_kernel<float><<<dim3(Dm / 128, M / 128), 256, 0, stream>>>(
        AOb, woT, out, M, Dm, Dm);
}

// Round 7
// 317.342 us; speedup vs baseline: 1.0880x; 1.0880x over previous
//
#include <hip/hip_runtime.h>
#include <hip/hip_bf16.h>
#include <math.h>

#define Bsz 2
#define Sq  2048
#define Dm  2048
#define Hn  16
#define KVn 4
#define HDn 128

typedef __attribute__((ext_vector_type(8))) short bf16x8;
typedef __attribute__((ext_vector_type(4))) float f32x4;

__device__ __forceinline__ short f2b(float f) {
    __hip_bfloat16 h = __float2bfloat16(f);
    return *reinterpret_cast<short*>(&h);
}
__device__ __forceinline__ float b2f(short s) {
    __hip_bfloat16 h = *reinterpret_cast<__hip_bfloat16*>(&s);
    return __bfloat162float(h);
}

// ------------- FUSED: fp32->bf16 (x) + all-weight transpose conversion -------------
// Blocks [0, NB_F2B): x -> xb elementwise. Blocks [NB_F2B, NB_F2B+NB_WC): weight
// transpose (rows 0..3071 -> wqkvT, 3072..5119 -> woT). One launch instead of two.
#define NB_F2B 8192
#define NB_WC  10240   // 160 x 64
__global__ __launch_bounds__(256) void prep_kernel(
    const float* __restrict__ X, short* __restrict__ Y,
    const float* __restrict__ wq, const float* __restrict__ wk,
    const float* __restrict__ wv, const float* __restrict__ wo,
    short* __restrict__ wqkvT, short* __restrict__ woT)
{
    __shared__ float t[32][33];
    const int bid = blockIdx.x;
    const int tid = threadIdx.x;

    if (bid < NB_F2B) {
        const int i = bid * 256 + tid;             // n4 = 8388608/4 = 2097152 > covered
        float4 v = ((const float4*)X)[i];
        short4 o;
        o.x = f2b(v.x); o.y = f2b(v.y); o.z = f2b(v.z); o.w = f2b(v.w);
        ((short4*)Y)[i] = o;
        return;
    }

    const int wb = bid - NB_F2B;
    const int n0 = (wb % 160) * 32;   // global output row
    const int k0 = (wb / 160) * 32;
    const int tx = tid & 31, ty = tid >> 5;

    const float* W; int Nsec, nloc; short* dst;
    if (n0 < 2048)      { W = wq; Nsec = 2048; nloc = n0;        dst = wqkvT + (size_t)n0 * Dm; }
    else if (n0 < 2560) { W = wk; Nsec = 512;  nloc = n0 - 2048; dst = wqkvT + (size_t)n0 * Dm; }
    else if (n0 < 3072) { W = wv; Nsec = 512;  nloc = n0 - 2560; dst = wqkvT + (size_t)n0 * Dm; }
    else                { W = wo; Nsec = 2048; nloc = n0 - 3072; dst = woT + (size_t)(n0 - 3072) * Dm; }

#pragma unroll
    for (int r = 0; r < 4; ++r) {
        const int row = ty + 8 * r;
        t[row][tx] = W[(size_t)(k0 + row) * Nsec + nloc + tx];
    }
    __syncthreads();
#pragma unroll
    for (int r = 0; r < 4; ++r) {
        const int row = ty + 8 * r;
        dst[(size_t)row * Dm + k0 + tx] = f2b(t[tx][row]);
    }
}

// ---------------- bf16 MFMA GEMM: C(MxN) = A(MxK) * Bt(NxK)^T ----------------
// T1: bijective XCD-aware block swizzle (requires nwg % 8 == 0; true for both
// launches: 768 and 512). Each XCD owns a contiguous band of output-row tiles
// -> A-band stays L2-resident per XCD instead of being fetched by all 8.
template <typename OT>
__global__ __launch_bounds__(256) void gemm_bt_kernel(
    const short* __restrict__ A, const short* __restrict__ Bt,
    OT* __restrict__ C, int M, int N, int K)
{
    __shared__ __align__(16) short As[128 * 64];
    __shared__ __align__(16) short Bs[128 * 64];

    const int tid  = threadIdx.x;
    const int w    = tid >> 6;
    const int lane = tid & 63;
    const int m16  = lane & 15;
    const int g4   = lane >> 4;
    const int wm   = w >> 1, wn = w & 1;

    // XCD swizzle
    const int nwg = gridDim.x * gridDim.y;
    const int lin = blockIdx.y * gridDim.x + blockIdx.x;
    const int qq  = nwg >> 3;
    const int sw  = (lin & 7) * qq + (lin >> 3);
    const int bx  = sw % gridDim.x;
    const int by  = sw / gridDim.x;

    const int row0 = by * 128;
    const int col0 = bx * 128;

    const short* Ab = A  + (size_t)row0 * K;
    const short* Bb = Bt + (size_t)col0 * K;

    const int trow = tid >> 3;
    const int soct = (tid & 7) ^ (trow & 7);

    f32x4 acc[4][4];
#pragma unroll
    for (int i = 0; i < 4; ++i)
#pragma unroll
        for (int j = 0; j < 4; ++j) acc[i][j] = (f32x4){0.f, 0.f, 0.f, 0.f};

    for (int k0 = 0; k0 < K; k0 += 64) {
#pragma unroll
        for (int r = 0; r < 4; ++r) {
            const short* gp = Ab + (size_t)(r * 32 + trow) * K + k0 + soct * 8;
            short* lp = &As[(size_t)(r * 256 + w * 64) * 8];
            __builtin_amdgcn_global_load_lds(
                (const __attribute__((address_space(1))) void*)gp,
                (__attribute__((address_space(3))) void*)lp, 16, 0, 0);
        }
#pragma unroll
        for (int r = 0; r < 4; ++r) {
            const short* gp = Bb + (size_t)(r * 32 + trow) * K + k0 + soct * 8;
            short* lp = &Bs[(size_t)(r * 256 + w * 64) * 8];
            __builtin_amdgcn_global_load_lds(
                (const __attribute__((address_space(1))) void*)gp,
                (__attribute__((address_space(3))) void*)lp, 16, 0, 0);
        }
        __syncthreads();

#pragma unroll
        for (int kc = 0; kc < 2; ++kc) {
            bf16x8 a[4], b[4];
            const int swz = (kc * 4 + g4) ^ (m16 & 7);
#pragma unroll
            for (int s = 0; s < 4; ++s) {
                const int rowA = wm * 64 + s * 16 + m16;
                a[s] = *(const bf16x8*)&As[rowA * 64 + swz * 8];
                const int rowB = wn * 64 + s * 16 + m16;
                b[s] = *(const bf16x8*)&Bs[rowB * 64 + swz * 8];
            }
#pragma unroll
            for (int i = 0; i < 4; ++i)
#pragma unroll
                for (int j = 0; j < 4; ++j)
                    acc[i][j] = __builtin_amdgcn_mfma_f32_16x16x32_bf16(
                        a[i], b[j], acc[i][j], 0, 0, 0);
        }
        __syncthreads();
    }

#pragma unroll
    for (int i = 0; i < 4; ++i) {
        const int mbase = row0 + wm * 64 + i * 16 + g4 * 4;
#pragma unroll
        for (int j = 0; j < 4; ++j) {
            const int n = col0 + wn * 64 + j * 16 + m16;
#pragma unroll
            for (int r = 0; r < 4; ++r) {
                if constexpr (sizeof(OT) == 2)
                    C[(size_t)(mbase + r) * N + n] = f2b(acc[i][j][r]);
                else
                    C[(size_t)(mbase + r) * N + n] = acc[i][j][r];
            }
        }
    }
}

// ------------- FUSED: RoPE (Q+K) + V transpose, one launch -------------
// Blocks [0, NB_ROPE): rope, one thread per (b,s,i), sincos computed once for
// all 20 heads. Blocks [NB_ROPE, NB_ROPE+NB_VC): V region of C3 -> (B,KV,HD,S).
#define NB_ROPE 1024
#define NB_VC   2048   // 64 x 4 x 8
__global__ __launch_bounds__(256) void rv_kernel(
    const short* __restrict__ C3b, short* __restrict__ Qb, short* __restrict__ Kb,
    short* __restrict__ Vt, const int* __restrict__ pos_ids, float qscale)
{
    __shared__ short tv[32][34];
    const int bid = blockIdx.x;
    const int tid = threadIdx.x;

    if (bid < NB_ROPE) {
        const int idx = bid * 256 + tid;
        const int i = idx & 63;
        int rest = idx >> 6;
        const int s = rest % Sq;
        const int b = rest / Sq;

        const int pos = pos_ids[b * Sq + s];
        const float e   = -(float)(2 * i) * (1.0f / (float)HDn);
        const float inv = exp2f(e * 18.931568569324174f);   // log2(500000)
        const float f   = (float)pos * inv;
        float sn, c;
        sincosf(f, &sn, &c);

        const short* src = C3b + ((size_t)(b * Sq + s)) * 3072;

#pragma unroll
        for (int h = 0; h < Hn; ++h) {
            const float x1 = b2f(src[h * HDn + i]);
            const float x2 = b2f(src[h * HDn + i + 64]);
            const size_t dst = (((size_t)b * Hn + h) * Sq + s) * HDn;
            Qb[dst + i]      = f2b((x1 * c - x2 * sn) * qscale);
            Qb[dst + i + 64] = f2b((x2 * c + x1 * sn) * qscale);
        }
#pragma unroll
        for (int h = 0; h < KVn; ++h) {
            const float x1 = b2f(src[2048 + h * HDn + i]);
            const float x2 = b2f(src[2048 + h * HDn + i + 64]);
            const size_t dst = (((size_t)b * KVn + h) * Sq + s) * HDn;
            Kb[dst + i]      = f2b(x1 * c - x2 * sn);
            Kb[dst + i + 64] = f2b(x2 * c + x1 * sn);
        }
        return;
    }

    const int lin = bid - NB_ROPE;
    const int bxv = lin & 63;           // Sq/32
    const int rest = lin >> 6;
    const int byv = rest & 3;           // HDn/32
    const int bk  = rest >> 2;          // Bsz*KVn
    const int b  = bk >> 2, kv = bk & 3;
    const int s0 = bxv * 32;
    const int d0 = byv * 32;
    const int tx = tid & 31, ty = tid >> 5;

#pragma unroll
    for (int r = 0; r < 4; ++r) {
        const int row = ty + 8 * r;
        tv[row][tx] = C3b[((size_t)(b * Sq + s0 + row)) * 3072 + 2560 + kv * HDn + d0 + tx];
    }
    __syncthreads();
#pragma unroll
    for (int r = 0; r < 4; ++r) {
        const int row = ty + 8 * r;
        Vt[((size_t)bk * HDn + d0 + row) * Sq + s0 + tx] = tv[tx][row];
    }
}

// ------------- Block-cooperative MFMA flash attention, KQ orientation -------------
// R5-verified DUAL-TILE NESTED structure (70.2 us). 512 blocks x 4 waves
// (2 blocks/CU). Block p owns nested 64-row tiles htA=31-p, htB=p off one
// staging stream of 32-p chunks: dual phase (K/V-frag reads shared by 2 MFMAs)
// then solo phase for tile A. Balanced mapping pairs complementary p on
// co-resident blocks.
__global__ __launch_bounds__(256, 2) void fattn_kernel(
    const short* __restrict__ Qb, const short* __restrict__ Kb,
    const short* __restrict__ Vtb, short* __restrict__ AOb)
{
    __shared__ __align__(16) short Ks[2][64 * 128];   // [buf][perm key][dim], oct-swizzled
    __shared__ __align__(16) short Vs[2][128 * 64];   // [buf][dim][key], oct-swizzled

    const int tid  = threadIdx.x;
    const int w    = tid >> 6;
    const int lane = tid & 63;
    const int m16  = lane & 15;
    const int g4   = lane >> 4;

    // balanced mapping: blocks i and i+256 get complementary p
    const int i    = blockIdx.x;
    const int half = i >> 8;
    const int k4   = i & 15;
    const int p    = half ? k4 : 15 - k4;
    const int h    = (i >> 4) & 15;
    const int b    = i >> 8;
    const int kv   = h >> 2;

    const int htA = 31 - p, htB = p;    // nested 64-row tiles
    const int nch = htA + 1;            // staged/computed chunks: 32-p
    const int qA  = htA * 64 + w * 16;  // this wave's q-row base, tile A
    const int qB  = htB * 64 + w * 16;

    // Q fragments for both tiles
    bf16x8 qfA[4], qfB[4];
    {
        const short* qpA = Qb + (((size_t)b * Hn + h) * Sq + qA + m16) * HDn + g4 * 8;
        const short* qpB = Qb + (((size_t)b * Hn + h) * Sq + qB + m16) * HDn + g4 * 8;
#pragma unroll
        for (int c = 0; c < 4; ++c) {
            qfA[c] = *(const bf16x8*)(qpA + c * 32);
            qfB[c] = *(const bf16x8*)(qpB + c * 32);
        }
    }

    const short* kbase = Kb  + ((size_t)b * KVn + kv) * Sq * HDn;
    const short* vbase = Vtb + ((size_t)b * KVn + kv) * (size_t)HDn * Sq;

    // staging source pointers (loop-invariant part); 256 threads x r=0..3 x 16B
    const short* gpK[4];
    const short* gpV[4];
#pragma unroll
    for (int r = 0; r < 4; ++r) {
        const int ci = r * 256 + tid;
        const int R  = ci >> 4, o = ci & 15;          // LDS K row, oct
        const int hf = (R >> 5) & 1, Rl = R & 31;
        const int phys = hf * 32 + ((Rl >> 2) & 3) * 8 + ((Rl >> 4) & 1) * 4 + (Rl & 3);
        gpK[r] = kbase + (size_t)phys * HDn + (o ^ (R & 7)) * 8;
        const int d = ci >> 3, ov = ci & 7;           // V dim row, oct
        gpV[r] = vbase + (size_t)d * Sq + (ov ^ (d & 7)) * 8;
    }

    auto stage = [&](int ktE, int buf) {
#pragma unroll
        for (int r = 0; r < 4; ++r) {
            const short* gp = gpK[r] + (size_t)ktE * HDn;
            short* lp = &Ks[buf][(size_t)(r * 256 + w * 64) * 8];
            __builtin_amdgcn_global_load_lds(
                (const __attribute__((address_space(1))) void*)gp,
                (__attribute__((address_space(3))) void*)lp, 16, 0, 0);
        }
#pragma unroll
        for (int r = 0; r < 4; ++r) {
            const short* gp = gpV[r] + ktE;
            short* lp = &Vs[buf][(size_t)(r * 256 + w * 64) * 8];
            __builtin_amdgcn_global_load_lds(
                (const __attribute__((address_space(1))) void*)gp,
                (__attribute__((address_space(3))) void*)lp, 16, 0, 0);
        }
    };

    f32x4 OtA[8], OtB[8];
#pragma unroll
    for (int t = 0; t < 8; ++t) {
        OtA[t] = (f32x4){0.f, 0.f, 0.f, 0.f};
        OtB[t] = (f32x4){0.f, 0.f, 0.f, 0.f};
    }
    float mA = -1e30f, lA = 0.f, mB = -1e30f, lB = 0.f;

    stage(0, 0);
    int gpar = 0;

    // ================= dual phase: chunks 0..p (tile B ends at p) =========
    for (int ch = 0; ch <= p; ++ch) {
        const int cur = gpar & 1; gpar ^= 1;
        const int kt  = ch << 6;

        __syncthreads();                     // buf[cur] staged; prior readers of buf[cur^1] done
        stage((ch + 1) << 6, cur ^ 1);       // ch+1 <= p+1 <= 31-p always valid

        const bool dgB = (ch == p);          // tile B diagonal chunk
        const short* KsC = Ks[cur];
        const short* VsC = Vs[cur];

        // ---- scores, K-frag read shared by both tiles ----
        f32x4 sc0[4], sc1[4];
        __builtin_amdgcn_s_setprio(1);
#pragma unroll
        for (int f = 0; f < 4; ++f) {
            f32x4 a0 = (f32x4){0.f, 0.f, 0.f, 0.f};
            f32x4 a1 = (f32x4){0.f, 0.f, 0.f, 0.f};
            const int krow = f * 16 + m16;
#pragma unroll
            for (int c = 0; c < 4; ++c) {
                bf16x8 kf = *(const bf16x8*)&KsC[krow * 128 + (((c * 4 + g4) ^ (m16 & 7)) * 8)];
                a0 = __builtin_amdgcn_mfma_f32_16x16x32_bf16(kf, qfA[c], a0, 0, 0, 0);
                a1 = __builtin_amdgcn_mfma_f32_16x16x32_bf16(kf, qfB[c], a1, 0, 0, 0);
            }
            sc0[f] = a0; sc1[f] = a1;
        }
        __builtin_amdgcn_s_setprio(0);

        // tile A never hits its diagonal during the dual phase (htA >= 16 > p)
        if (dgB) {
            const int qg = qB + m16;
#pragma unroll
            for (int f = 0; f < 4; ++f)
#pragma unroll
                for (int ii = 0; ii < 4; ++ii) {
                    const int kg = kt + (f >> 1) * 32 + g4 * 8 + (f & 1) * 4 + ii;
                    if (kg > qg) sc1[f][ii] = -1e30f;
                }
        }

        // ---- online softmax, tile A ----
        bf16x8 pf0[2], pf1[2];
        {
            float mx = sc0[0][0];
#pragma unroll
            for (int f = 0; f < 4; ++f)
#pragma unroll
                for (int ii = 0; ii < 4; ++ii) mx = fmaxf(mx, sc0[f][ii]);
            mx = fmaxf(mx, __shfl_xor(mx, 16));
            mx = fmaxf(mx, __shfl_xor(mx, 32));
            if (!__all(mx <= mA + 8.0f)) {
                const float nm = fmaxf(mA, mx);
                const float alpha = exp2f(mA - nm);
                mA = nm; lA *= alpha;
#pragma unroll
                for (int t = 0; t < 8; ++t)
#pragma unroll
                    for (int ii = 0; ii < 4; ++ii) OtA[t][ii] *= alpha;
            }
            float ps = 0.f;
#pragma unroll
            for (int f = 0; f < 4; ++f)
#pragma unroll
                for (int ii = 0; ii < 4; ++ii) {
                    sc0[f][ii] = exp2f(sc0[f][ii] - mA);
                    ps += sc0[f][ii];
                }
            ps += __shfl_xor(ps, 16);
            ps += __shfl_xor(ps, 32);
            lA += ps;
#pragma unroll
            for (int hf = 0; hf < 2; ++hf) {
                bf16x8 pk;
#pragma unroll
                for (int j8 = 0; j8 < 8; ++j8)
                    pk[j8] = f2b(j8 < 4 ? sc0[hf * 2][j8] : sc0[hf * 2 + 1][j8 - 4]);
                pf0[hf] = pk;
            }
        }
        // ---- online softmax, tile B ----
        {
            float mx = sc1[0][0];
#pragma unroll
            for (int f = 0; f < 4; ++f)
#pragma unroll
                for (int ii = 0; ii < 4; ++ii) mx = fmaxf(mx, sc1[f][ii]);
            mx = fmaxf(mx, __shfl_xor(mx, 16));
            mx = fmaxf(mx, __shfl_xor(mx, 32));
            if (!__all(mx <= mB + 8.0f)) {
                const float nm = fmaxf(mB, mx);
                const float alpha = exp2f(mB - nm);
                mB = nm; lB *= alpha;
#pragma unroll
                for (int t = 0; t < 8; ++t)
#pragma unroll
                    for (int ii = 0; ii < 4; ++ii) OtB[t][ii] *= alpha;
            }
            float ps = 0.f;
#pragma unroll
            for (int f = 0; f < 4; ++f)
#pragma unroll
                for (int ii = 0; ii < 4; ++ii) {
                    sc1[f][ii] = exp2f(sc1[f][ii] - mB);
                    ps += sc1[f][ii];
                }
            ps += __shfl_xor(ps, 16);
            ps += __shfl_xor(ps, 32);
            lB += ps;
#pragma unroll
            for (int hf = 0; hf < 2; ++hf) {
                bf16x8 pk;
#pragma unroll
                for (int j8 = 0; j8 < 8; ++j8)
                    pk[j8] = f2b(j8 < 4 ? sc1[hf * 2][j8] : sc1[hf * 2 + 1][j8 - 4]);
                pf1[hf] = pk;
            }
        }

        // ---- PV: V-frag read shared by both tiles ----
        __builtin_amdgcn_s_setprio(1);
#pragma unroll
        for (int t = 0; t < 8; ++t) {
            const int d = t * 16 + m16;
            bf16x8 vfa = *(const bf16x8*)&VsC[d * 64 + ((g4 ^ (d & 7)) * 8)];
            bf16x8 vfb = *(const bf16x8*)&VsC[d * 64 + (((4 + g4) ^ (d & 7)) * 8)];
            OtA[t] = __builtin_amdgcn_mfma_f32_16x16x32_bf16(vfa, pf0[0], OtA[t], 0, 0, 0);
            OtA[t] = __builtin_amdgcn_mfma_f32_16x16x32_bf16(vfb, pf0[1], OtA[t], 0, 0, 0);
            OtB[t] = __builtin_amdgcn_mfma_f32_16x16x32_bf16(vfa, pf1[0], OtB[t], 0, 0, 0);
            OtB[t] = __builtin_amdgcn_mfma_f32_16x16x32_bf16(vfb, pf1[1], OtB[t], 0, 0, 0);
        }
        __builtin_amdgcn_s_setprio(0);
    }

    // tile B complete -> write its output now
    {
        const float inv = 1.0f / lB;
        short* op = AOb + ((size_t)(b * Sq + qB + m16)) * (Hn * HDn) + h * HDn + g4 * 4;
#pragma unroll
        for (int t = 0; t < 8; ++t) {
            short4 o;
            o.x = f2b(OtB[t][0] * inv);
            o.y = f2b(OtB[t][1] * inv);
            o.z = f2b(OtB[t][2] * inv);
            o.w = f2b(OtB[t][3] * inv);
            *(short4*)(op + t * 16) = o;
        }
    }

    // ================= solo phase: chunks p+1..31-p (tile A only) =========
    for (int ch = p + 1; ch < nch; ++ch) {
        const int cur = gpar & 1; gpar ^= 1;
        const int kt  = ch << 6;

        __syncthreads();
        if (ch + 1 < nch) stage((ch + 1) << 6, cur ^ 1);

        const bool dgA = (ch == nch - 1);
        const short* KsC = Ks[cur];
        const short* VsC = Vs[cur];

        f32x4 sc[4];
        __builtin_amdgcn_s_setprio(1);
#pragma unroll
        for (int f = 0; f < 4; ++f) {
            f32x4 a = (f32x4){0.f, 0.f, 0.f, 0.f};
            const int krow = f * 16 + m16;
#pragma unroll
            for (int c = 0; c < 4; ++c) {
                bf16x8 kf = *(const bf16x8*)&KsC[krow * 128 + (((c * 4 + g4) ^ (m16 & 7)) * 8)];
                a = __builtin_amdgcn_mfma_f32_16x16x32_bf16(kf, qfA[c], a, 0, 0, 0);
            }
            sc[f] = a;
        }
        __builtin_amdgcn_s_setprio(0);

        if (dgA) {
            const int qg = qA + m16;
#pragma unroll
            for (int f = 0; f < 4; ++f)
#pragma unroll
                for (int ii = 0; ii < 4; ++ii) {
                    const int kg = kt + (f >> 1) * 32 + g4 * 8 + (f & 1) * 4 + ii;
                    if (kg > qg) sc[f][ii] = -1e30f;
                }
        }

        float mx = sc[0][0];
#pragma unroll
        for (int f = 0; f < 4; ++f)
#pragma unroll
            for (int ii = 0; ii < 4; ++ii) mx = fmaxf(mx, sc[f][ii]);
        mx = fmaxf(mx, __shfl_xor(mx, 16));
        mx = fmaxf(mx, __shfl_xor(mx, 32));
        if (!__all(mx <= mA + 8.0f)) {
            const float nm = fmaxf(mA, mx);
            const float alpha = exp2f(mA - nm);
            mA = nm; lA *= alpha;
#pragma unroll
            for (int t = 0; t < 8; ++t)
#pragma unroll
                for (int ii = 0; ii < 4; ++ii) OtA[t][ii] *= alpha;
        }
        float ps = 0.f;
#pragma unroll
        for (int f = 0; f < 4; ++f)
#pragma unroll
            for (int ii = 0; ii < 4; ++ii) {
                sc[f][ii] = exp2f(sc[f][ii] - mA);
                ps += sc[f][ii];
            }
        ps += __shfl_xor(ps, 16);
        ps += __shfl_xor(ps, 32);
        lA += ps;

        bf16x8 pf[2];
#pragma unroll
        for (int hf = 0; hf < 2; ++hf) {
            bf16x8 pk;
#pragma unroll
            for (int j8 = 0; j8 < 8; ++j8)
                pk[j8] = f2b(j8 < 4 ? sc[hf * 2][j8] : sc[hf * 2 + 1][j8 - 4]);
            pf[hf] = pk;
        }

        __builtin_amdgcn_s_setprio(1);
#pragma unroll
        for (int t = 0; t < 8; ++t) {
            const int d = t * 16 + m16;
            bf16x8 vfa = *(const bf16x8*)&VsC[d * 64 + ((g4 ^ (d & 7)) * 8)];
            bf16x8 vfb = *(const bf16x8*)&VsC[d * 64 + (((4 + g4) ^ (d & 7)) * 8)];
            OtA[t] = __builtin_amdgcn_mfma_f32_16x16x32_bf16(vfa, pf[0], OtA[t], 0, 0, 0);
            OtA[t] = __builtin_amdgcn_mfma_f32_16x16x32_bf16(vfb, pf[1], OtA[t], 0, 0, 0);
        }
        __builtin_amdgcn_s_setprio(0);
    }

    // tile A epilogue
    {
        const float inv = 1.0f / lA;
        short* op = AOb + ((size_t)(b * Sq + qA + m16)) * (Hn * HDn) + h * HDn + g4 * 4;
#pragma unroll
        for (int t = 0; t < 8; ++t) {
            short4 o;
            o.x = f2b(OtA[t][0] * inv);
            o.y = f2b(OtA[t][1] * inv);
            o.z = f2b(OtA[t][2] * inv);
            o.w = f2b(OtA[t][3] * inv);
            *(short4*)(op + t * 16) = o;
        }
    }
}

extern "C" void kernel_launch(void* const* d_in, const int* in_sizes, int n_in,
                              void* d_out, int out_size, void* d_ws, size_t ws_size,
                              hipStream_t stream)
{
    const float* x   = (const float*)d_in[0];
    const float* wq  = (const float*)d_in[1];
    const float* wk  = (const float*)d_in[2];
    const float* wv  = (const float*)d_in[3];
    const float* wo  = (const float*)d_in[4];
    const int* pos   = (const int*)d_in[6];
    float* out = (float*)d_out;

    const int M = Bsz * Sq;            // 4096
    const size_t nX  = (size_t)M * Dm; // 8388608

    short* xb    = (short*)d_ws;
    short* wqkvT = xb + nX;                       // 3072 x 2048
    short* woT   = wqkvT + (size_t)3072 * Dm;     // 2048 x 2048
    short* C3b   = woT + (size_t)Dm * Dm;         // 4096 x 3072 bf16
    short* Qb    = C3b + (size_t)M * 3072;
    short* Kb    = Qb + nX;
    short* Vtb   = Kb + (size_t)Bsz * KVn * Sq * HDn;
    short* AOb   = Vtb + (size_t)Bsz * KVn * Sq * HDn;

    // --- fused conversions (1 launch) ---
    prep_kernel<<<NB_F2B + NB_WC, 256, 0, stream>>>(
        x, xb, wq, wk, wv, wo, wqkvT, woT);

    // --- fused QKV projection -> bf16 C3 (XCD-swizzled) ---
    gemm_bt_kernel<short><<<dim3(3072 / 128, M / 128), 256, 0, stream>>>(
        xb, wqkvT, C3b, M, 3072, Dm);

    // --- fused RoPE (Q+K) + V transpose (1 launch) ---
    {
        const float qscale = 0.08838834764831845f * 1.4426950408889634f;
        rv_kernel<<<NB_ROPE + NB_VC, 256, 0, stream>>>(
            C3b, Qb, Kb, Vtb, pos, qscale);
    }

    // --- attention: 512 blocks, nested dual-tile, shared-read staging (R5) ---
    fattn_kernel<<<Bsz * Hn * 16, 256, 0, stream>>>(Qb, Kb, Vtb, AOb);

    // --- output projection (fp32 out, XCD-swizzled) ---
    gemm_bt_kernel<float><<<dim3(Dm / 128, M / 128), 256, 0, stream>>>(
        AOb, woT, out, M, Dm, Dm);
}